// Round 16
// baseline (105.976 us; speedup 1.0000x reference)
//
#include <hip/hip_runtime.h>
#include <hip/hip_bf16.h>

#define EMB 768
#define HEADS 12
#define DKV 64
#define BATCH 2
#define SEQ 2048
#define NTOK (BATCH*SEQ)   // 4096

typedef float f32x4 __attribute__((ext_vector_type(4)));
typedef unsigned short u16;
typedef u16 u16x8 __attribute__((ext_vector_type(8)));
typedef u16 u16x4 __attribute__((ext_vector_type(4)));
typedef __bf16 bf16x8 __attribute__((ext_vector_type(8)));

__device__ __forceinline__ u16 f2bf(float f) {
  return __builtin_bit_cast(u16, (__bf16)f);
}
__device__ __forceinline__ float fexp2(float x) {
#if __has_builtin(__builtin_amdgcn_exp2f)
  return __builtin_amdgcn_exp2f(x);
#else
  return exp2f(x);
#endif
}
__device__ __forceinline__ f32x4 mfma16(u16x8 a, u16x8 b, f32x4 c) {
  return __builtin_amdgcn_mfma_f32_16x16x32_bf16(
      __builtin_bit_cast(bf16x8, a), __builtin_bit_cast(bf16x8, b), c, 0, 0, 0);
}
// async global->LDS, 16B/lane; LDS dest = wave-uniform base + lane*16 (implicit)
__device__ __forceinline__ void gload16(const void* g, void* l) {
  __builtin_amdgcn_global_load_lds(
      (const __attribute__((address_space(1))) void*)g,
      (__attribute__((address_space(3))) void*)l, 16, 0, 0);
}

// ---------------- cast pass: 4 W's fp32 -> bf16 (x casts fused into qkv) ----------------
__global__ void cast_w_k(
    const float* __restrict__ w0, const float* __restrict__ w1,
    const float* __restrict__ w2, const float* __restrict__ w3,
    u16* __restrict__ W0, u16* __restrict__ W1, u16* __restrict__ W2, u16* __restrict__ W3)
{
  const int NW = EMB*EMB/8;    // 73728
  int i = blockIdx.x*256 + threadIdx.x;
  if (i >= 4*NW) return;
  int which = i / NW, off = i - which*NW;
  const float* s = which==0 ? w0 : which==1 ? w1 : which==2 ? w2 : w3;
  u16* d        = which==0 ? W0 : which==1 ? W1 : which==2 ? W2 : W3;
  float4 a = reinterpret_cast<const float4*>(s)[off*2];
  float4 b = reinterpret_cast<const float4*>(s)[off*2+1];
  u16x8 o;
  o[0]=f2bf(a.x); o[1]=f2bf(a.y); o[2]=f2bf(a.z); o[3]=f2bf(a.w);
  o[4]=f2bf(b.x); o[5]=f2bf(b.y); o[6]=f2bf(b.z); o[7]=f2bf(b.w);
  reinterpret_cast<u16x8*>(d)[off] = o;
}

// ---------------- GEMM core: 64x128 tile, double-buffered, 1 barrier/step (r15) ----------------
template<int MODE, bool AF32>
__device__ __forceinline__ void gemm_core(
    const void* __restrict__ Ap, const u16* __restrict__ Bm,
    const float* __restrict__ bias, float ascale, float bscale,
    void* __restrict__ outp, u16* __restrict__ At, u16* __restrict__ Bt,
    int m0, int n0)
{
  const int t = threadIdx.x;
  const int w = t >> 6, lane = t & 63, lg = lane >> 4, lr = lane & 15;
  const int wr = w >> 1, wc = w & 1;
  const int lrow = lane >> 3, csl = lane & 7;

  f32x4 acc[2][4] = {};
  f32x4 raf[2][2];

  auto A_LOAD = [&](int kb) {
    #pragma unroll
    for (int q2 = 0; q2 < 2; ++q2) {
      int c = q2*256 + t, row = c >> 3, sl = c & 7;
      const float* p = (const float*)Ap + (size_t)(m0+row)*EMB + kb + sl*8;
      raf[q2][0] = *reinterpret_cast<const f32x4*>(p);
      raf[q2][1] = *reinterpret_cast<const f32x4*>(p + 4);
    }
  };
  auto A_WRITE = [&](int bi) {
    #pragma unroll
    for (int q2 = 0; q2 < 2; ++q2) {
      int c = q2*256 + t, row = c >> 3, sl = c & 7;
      u16x8 v;
      #pragma unroll
      for (int j = 0; j < 4; ++j) {
        v[j]   = f2bf(raf[q2][0][j] * ascale);
        v[4+j] = f2bf(raf[q2][1][j] * ascale);
      }
      *reinterpret_cast<u16x8*>(&At[bi*4096 + row*64 + ((sl ^ (row & 7))*8)]) = v;
    }
  };
  auto A_GLOAD = [&](int kb, int bi) {
    #pragma unroll
    for (int i = 0; i < 2; ++i) {
      int ci = w*2 + i;
      int row = ci*8 + lrow;
      int sg = csl ^ (row & 7);
      gload16((const u16*)Ap + (size_t)(m0+row)*EMB + kb + sg*8,
              &At[bi*4096 + ci*512]);
    }
  };
  auto B_GLOAD = [&](int kb, int bi) {
    #pragma unroll
    for (int i = 0; i < 4; ++i) {
      int ci = w*4 + i;
      int row = ci*8 + lrow;
      int sg = csl ^ (row & 7);
      gload16(Bm + (size_t)(n0+row)*EMB + kb + sg*8, &Bt[bi*8192 + ci*512]);
    }
  };

  auto COMPUTE = [&](int bi) {
    u16x8 af[2][2], bf[4][2];
    #pragma unroll
    for (int fm = 0; fm < 2; ++fm)
      #pragma unroll
      for (int kk = 0; kk < 2; ++kk) {
        int r = wr*32 + fm*16 + lr;
        int p = (lg + 4*kk) ^ (r & 7);
        af[fm][kk] = *reinterpret_cast<const u16x8*>(&At[bi*4096 + r*64 + p*8]);
      }
    #pragma unroll
    for (int fn = 0; fn < 4; ++fn)
      #pragma unroll
      for (int kk = 0; kk < 2; ++kk) {
        int r = wc*64 + fn*16 + lr;
        int p = (lg + 4*kk) ^ (r & 7);
        bf[fn][kk] = *reinterpret_cast<const u16x8*>(&Bt[bi*8192 + r*64 + p*8]);
      }
    __builtin_amdgcn_s_setprio(1);
    #pragma unroll
    for (int fm = 0; fm < 2; ++fm)
      #pragma unroll
      for (int fn = 0; fn < 4; ++fn)
        #pragma unroll
        for (int kk = 0; kk < 2; ++kk)
          acc[fm][fn] = mfma16(af[fm][kk], bf[fn][kk], acc[fm][fn]);
    __builtin_amdgcn_s_setprio(0);
  };

  const int NSTEP = EMB/64;   // 12
  if constexpr (AF32) {
    A_LOAD(0);
    B_GLOAD(0, 0);
    A_WRITE(0);
    __syncthreads();
    #pragma unroll
    for (int ts = 0; ts < NSTEP; ++ts) {
      if (ts+1 < NSTEP) {
        A_LOAD((ts+1)*64);
        B_GLOAD((ts+1)*64, (ts & 1) ^ 1);
      }
      COMPUTE(ts & 1);
      if (ts+1 < NSTEP) {
        A_WRITE((ts & 1) ^ 1);
        __syncthreads();
      }
    }
  } else {
    A_GLOAD(0, 0);
    B_GLOAD(0, 0);
    __syncthreads();
    #pragma unroll
    for (int ts = 0; ts < NSTEP; ++ts) {
      if (ts+1 < NSTEP) {
        A_GLOAD((ts+1)*64, (ts & 1) ^ 1);
        B_GLOAD((ts+1)*64, (ts & 1) ^ 1);
      }
      COMPUTE(ts & 1);
      if (ts+1 < NSTEP) __syncthreads();
    }
  }

  #pragma unroll
  for (int fm = 0; fm < 2; ++fm)
    #pragma unroll
    for (int fn = 0; fn < 4; ++fn) {
      const int mb = m0 + wr*32 + fm*16 + lg*4;
      const int e  = n0 + wc*64 + fn*16 + lr;
      if constexpr (MODE == 2) {
        int bb = mb >> 11, sb = mb & 2047, h = e >> 6, d = e & 63;
        u16x4 o4;
        #pragma unroll
        for (int j = 0; j < 4; ++j) o4[j] = f2bf(acc[fm][fn][j] + bias[e]*bscale);
        *reinterpret_cast<u16x4*>(
            reinterpret_cast<u16*>(outp) + (((size_t)(bb*HEADS+h))*DKV + d)*SEQ + sb) = o4;
      } else {
        #pragma unroll
        for (int j = 0; j < 4; ++j) {
          int m = mb + j;
          float val = acc[fm][fn][j] + bias[e]*bscale;
          if constexpr (MODE == 0) {
            int bb = m >> 11, s = m & 2047, h = e >> 6, d = e & 63;
            reinterpret_cast<u16*>(outp)[(((size_t)(bb*HEADS+h))*SEQ + s)*DKV + d] = f2bf(val);
          } else {
            reinterpret_cast<float*>(outp)[(size_t)m*EMB + e] = val;
          }
        }
      }
    }
}

__global__ __launch_bounds__(256) void qkv_k(
    const float* __restrict__ Xq, const float* __restrict__ Xk, const float* __restrict__ Xv,
    const u16* __restrict__ Wq, const u16* __restrict__ Wk, const u16* __restrict__ Wv,
    const float* __restrict__ bq, const float* __restrict__ bk, const float* __restrict__ bv,
    u16* __restrict__ Qh, u16* __restrict__ Kh, u16* __restrict__ Vh, float csc)
{
  __shared__ __align__(16) u16 At[2*64*64];
  __shared__ __align__(16) u16 Bt[2*128*64];
  const int m0 = blockIdx.x*64, n0 = blockIdx.y*128;
  const int z = blockIdx.z;
  if (z == 0)
    gemm_core<0,true>(Xq, Wq, bq, csc, csc, Qh, At, Bt, m0, n0);
  else if (z == 1)
    gemm_core<0,true>(Xk, Wk, bk, 1.f, 1.f, Kh, At, Bt, m0, n0);
  else
    gemm_core<2,true>(Xv, Wv, bv, 1.f, 1.f, Vh, At, Bt, m0, n0);
}

__global__ __launch_bounds__(256) void gemm_out_k(
    const u16* __restrict__ A, const u16* __restrict__ Bm,
    const float* __restrict__ bias, float* __restrict__ outp)
{
  __shared__ __align__(16) u16 At[2*64*64];
  __shared__ __align__(16) u16 Bt[2*128*64];
  gemm_core<1,false>(A, Bm, bias, 1.f, 1.f, outp, At, Bt, blockIdx.x*64, blockIdx.y*128);
}

// ---------------- flash attention: 2 waves x 32 q-rows (K/V reads amortized 2x) ----------------
// Same math/addressing as r14, but each wave owns TWO 16-row q-groups: every
// K/V LDS fragment is read ONCE and feeds two MFMAs (one per q-group), halving
// per-q LDS-read traffic on the ~81%-utilized LDS pipe. Grid/LDS/blocks-per-CU
// unchanged (768 blocks, 40 KB, 3/CU); waves/block 4->2.
__global__ __launch_bounds__(128) void flash_attn_k(
    const u16* __restrict__ Q, const u16* __restrict__ K, const u16* __restrict__ VT,
    u16* __restrict__ av)
{
  __shared__ __align__(16) u16 Kt[2][64*64];     // [key][d]: phys p of row r = logical p^(r&7)
  __shared__ __align__(16) u16 Vt[2][64*64];     // [d][key]: same relation
  __shared__ __align__(16) u16 Pt[2][2][16*64];  // [wave][qg] swizzled

  const int t = threadIdx.x;                     // 0..127
  const int w = t >> 6, lane = t & 63, lg = lane >> 4, lr = lane & 15;
  const int qb = blockIdx.x;       // 0..31
  const int bh = blockIdx.y;       // 0..23
  const u16* Qb = Q  + (size_t)bh*SEQ*DKV;
  const u16* Kb = K  + (size_t)bh*SEQ*DKV;
  const u16* Vb = VT + (size_t)bh*DKV*SEQ;

  // q-rows: qg 0/1 -> qb*64 + w*32 + qg*16 + lr
  const int qr0 = qb*64 + w*32 + lr;
  u16x8 qf0[2], qf1[2];
  qf0[0] = *reinterpret_cast<const u16x8*>(Qb + (size_t)qr0*DKV + lg*8);
  qf0[1] = *reinterpret_cast<const u16x8*>(Qb + (size_t)qr0*DKV + 32 + lg*8);
  qf1[0] = *reinterpret_cast<const u16x8*>(Qb + (size_t)(qr0+16)*DKV + lg*8);
  qf1[1] = *reinterpret_cast<const u16x8*>(Qb + (size_t)(qr0+16)*DKV + 32 + lg*8);

  f32x4 acc0[4] = {}, acc1[4] = {};
  float mrun0 = -1e30f, lrun0 = 0.f;
  float mrun1 = -1e30f, lrun1 = 0.f;

  auto STAGE = [&](int kt0, int bi) {
    #pragma unroll
    for (int c4 = 0; c4 < 4; ++c4) {
      int c = c4*128 + t;                 // 16B chunk 0..511
      int row = c >> 3, sl = c & 7;
      int sg = sl ^ (row & 7);            // pre-swizzled source slot
      gload16(Kb + (size_t)(kt0+row)*DKV + sg*8, &Kt[bi][c*8]);
    }
    #pragma unroll
    for (int c4 = 0; c4 < 4; ++c4) {
      int c = c4*128 + t;
      int row = c >> 3, sl = c & 7;       // row = d
      int sg = sl ^ (row & 7);
      gload16(Vb + (size_t)row*SEQ + kt0 + sg*8, &Vt[bi][c*8]);
    }
  };

  const int NT = SEQ/64;   // 32
  char* Pw0 = reinterpret_cast<char*>(&Pt[w][0][0]);
  char* Pw1 = reinterpret_cast<char*>(&Pt[w][1][0]);

// per-q-group softmax + P write (tokens: S=score regs, MR/LR=running, ACC, PB=P base)
#define SOFTPW(S, MR, LR, ACC, PB)                                            \
  do {                                                                        \
    float a0 = fmaxf(fmaxf(S[0][0], S[0][1]), S[0][2]);                       \
    float a1 = fmaxf(fmaxf(S[0][3], S[1][0]), S[1][1]);                       \
    float a2 = fmaxf(fmaxf(S[1][2], S[1][3]), S[2][0]);                       \
    float a3 = fmaxf(fmaxf(S[2][1], S[2][2]), S[2][3]);                       \
    float a4 = fmaxf(fmaxf(S[3][0], S[3][1]), S[3][2]);                       \
    float pmax = fmaxf(fmaxf(fmaxf(a0, a1), a2),                              \
                       fmaxf(fmaxf(a3, a4), S[3][3]));                        \
    if (__any(pmax > MR + 8.f)) {                                             \
      float pm = fmaxf(pmax, __shfl_xor(pmax, 16));                           \
      pm = fmaxf(pm, __shfl_xor(pm, 32));                                     \
      float mnew = fmaxf(MR, pm);                                             \
      float corr = fexp2(MR - mnew);                                          \
      MR = mnew; LR *= corr;                                                  \
      _Pragma("unroll")                                                       \
      for (int fc = 0; fc < 4; ++fc)                                          \
        _Pragma("unroll")                                                     \
        for (int j = 0; j < 4; ++j)                                           \
          ACC[fc][j] *= corr;                                                 \
    }                                                                         \
    float p_[4][4], rs_[4];                                                   \
    _Pragma("unroll")                                                         \
    for (int fc = 0; fc < 4; ++fc) {                                          \
      _Pragma("unroll")                                                       \
      for (int j = 0; j < 4; ++j) p_[fc][j] = fexp2(S[fc][j] - MR);           \
      rs_[fc] = (p_[fc][0] + p_[fc][1]) + (p_[fc][2] + p_[fc][3]);            \
    }                                                                         \
    LR += (rs_[0] + rs_[1]) + (rs_[2] + rs_[3]);                              \
    _Pragma("unroll")                                                         \
    for (int fc = 0; fc < 4; ++fc) {                                          \
      u16x4 q4;                                                               \
      _Pragma("unroll")                                                       \
      for (int j = 0; j < 4; ++j) q4[j] = f2bf(p_[fc][j]);                    \
      *reinterpret_cast<u16x4*>(                                              \
          PB + lr*128 + (((fc*4 + lg) ^ ((lr & 7) << 1))*8)) = q4;            \
    }                                                                         \
  } while (0)

#define TILE(bi, kt)                                                          \
  do {                                                                        \
    if ((kt)+1 < NT) STAGE(((kt)+1)*64, (bi)^1);                              \
    f32x4 s0[4], s1[4];                                                       \
    __builtin_amdgcn_s_setprio(1);                                            \
    _Pragma("unroll")                                                         \
    for (int fc = 0; fc < 4; ++fc) {                                          \
      f32x4 z0 = {}, z1 = {};                                                 \
      _Pragma("unroll")                                                       \
      for (int kk = 0; kk < 2; ++kk) {                                        \
        int r = fc*16 + lr;                                                   \
        int slot = (lg + 4*kk) ^ (r & 7);                                     \
        u16x8 kf = *reinterpret_cast<const u16x8*>(&Kt[bi][r*64 + slot*8]);   \
        z0 = mfma16(kf, qf0[kk], z0);                                         \
        z1 = mfma16(kf, qf1[kk], z1);                                         \
      }                                                                       \
      s0[fc] = z0; s1[fc] = z1;                                               \
    }                                                                         \
    __builtin_amdgcn_s_setprio(0);                                            \
    SOFTPW(s0, mrun0, lrun0, acc0, Pw0);                                      \
    SOFTPW(s1, mrun1, lrun1, acc1, Pw1);                                      \
    asm volatile("s_waitcnt lgkmcnt(0)" ::: "memory");                        \
    __builtin_amdgcn_sched_barrier(0);                                        \
    __builtin_amdgcn_s_setprio(1);                                            \
    _Pragma("unroll")                                                         \
    for (int kk = 0; kk < 2; ++kk) {                                          \
      int poff = (((kk*8 + lg*2) ^ ((lr & 7) << 1))*8) + lr*128;              \
      u16x8 pf0 = *reinterpret_cast<const u16x8*>(Pw0 + poff);                \
      u16x8 pf1 = *reinterpret_cast<const u16x8*>(Pw1 + poff);                \
      _Pragma("unroll")                                                       \
      for (int fc = 0; fc < 4; ++fc) {                                        \
        int rv = fc*16 + lr;                                                  \
        int slotv = (lg + 4*kk) ^ (rv & 7);                                   \
        u16x8 vf = *reinterpret_cast<const u16x8*>(&Vt[bi][rv*64 + slotv*8]); \
        acc0[fc] = mfma16(vf, pf0, acc0[fc]);                                 \
        acc1[fc] = mfma16(vf, pf1, acc1[fc]);                                 \
      }                                                                       \
    }                                                                         \
    __builtin_amdgcn_s_setprio(0);                                            \
    __syncthreads();                                                          \
  } while (0)

  STAGE(0, 0);
  __syncthreads();
  for (int kt = 0; kt < NT; kt += 2) {
    TILE(0, kt);
    TILE(1, kt+1);
  }
#undef TILE
#undef SOFTPW

  // epilogue: per q-group, combine partial l across the 4 partner lanes, store
  const int b = bh / HEADS, h = bh % HEADS;
  {
    float lt = lrun0;
    lt += __shfl_xor(lt, 16);
    lt += __shfl_xor(lt, 32);
    const float inv = 1.0f / lt;
    #pragma unroll
    for (int fc = 0; fc < 4; ++fc) {
      u16x4 o4;
      #pragma unroll
      for (int j = 0; j < 4; ++j) o4[j] = f2bf(acc0[fc][j] * inv);
      *reinterpret_cast<u16x4*>(
          av + ((size_t)(b*SEQ + qr0))*EMB + h*64 + fc*16 + lg*4) = o4;
    }
  }
  {
    float lt = lrun1;
    lt += __shfl_xor(lt, 16);
    lt += __shfl_xor(lt, 32);
    const float inv = 1.0f / lt;
    #pragma unroll
    for (int fc = 0; fc < 4; ++fc) {
      u16x4 o4;
      #pragma unroll
      for (int j = 0; j < 4; ++j) o4[j] = f2bf(acc1[fc][j] * inv);
      *reinterpret_cast<u16x4*>(
          av + ((size_t)(b*SEQ + qr0 + 16))*EMB + h*64 + fc*16 + lg*4) = o4;
    }
  }
}

// ---------------- launcher: 4 kernels ----------------
extern "C" void kernel_launch(void* const* d_in, const int* in_sizes, int n_in,
                              void* d_out, int out_size, void* d_ws, size_t ws_size,
                              hipStream_t stream) {
  const float* xq_f = (const float*)d_in[0];
  const float* xk_f = (const float*)d_in[1];
  const float* xv_f = (const float*)d_in[2];
  const float* Wq = (const float*)d_in[3];
  const float* bq = (const float*)d_in[4];
  const float* Wk = (const float*)d_in[5];
  const float* bk = (const float*)d_in[6];
  const float* Wv = (const float*)d_in[7];
  const float* bv = (const float*)d_in[8];
  const float* Wo = (const float*)d_in[9];
  const float* bo = (const float*)d_in[10];

  const size_t NX = (size_t)NTOK*EMB;
  const size_t NW = (size_t)EMB*EMB;
  u16* Wc0 = (u16*)d_ws;
  u16* Wc1 = Wc0 + NW;
  u16* Wc2 = Wc1 + NW;
  u16* Wc3 = Wc2 + NW;
  u16* Qh  = Wc3 + NW;
  u16* Kh  = Qh + NX;
  u16* Vh  = Kh + NX;        // [B][H][DKV][SEQ] (V^T)
  u16* Xb  = Vh + NX;        // attn output bf16

  const float csc = 0.125f * 1.4426950408889634f;  // folded into Q A-tile + bq

  cast_w_k<<<dim3(4*EMB*EMB/8/256), dim3(256), 0, stream>>>(
      Wq, Wk, Wv, Wo, Wc0, Wc1, Wc2, Wc3);

  qkv_k<<<dim3(NTOK/64, EMB/128, 3), dim3(256), 0, stream>>>(
      xq_f, xk_f, xv_f, Wc0, Wc1, Wc2, bq, bk, bv, Qh, Kh, Vh, csc);

  flash_attn_k<<<dim3(SEQ/64, BATCH*HEADS), dim3(128), 0, stream>>>(Qh, Kh, Vh, Xb);

  gemm_out_k<<<dim3(NTOK/64, EMB/128), dim3(256), 0, stream>>>(Xb, Wc3, bo, (float*)d_out);
}

// Round 17
// 95.086 us; speedup vs baseline: 1.1145x; 1.1145x over previous
//
#include <hip/hip_runtime.h>
#include <hip/hip_bf16.h>

#define EMB 768
#define HEADS 12
#define DKV 64
#define BATCH 2
#define SEQ 2048
#define NTOK (BATCH*SEQ)   // 4096

typedef float f32x4 __attribute__((ext_vector_type(4)));
typedef unsigned short u16;
typedef u16 u16x8 __attribute__((ext_vector_type(8)));
typedef u16 u16x4 __attribute__((ext_vector_type(4)));
typedef __bf16 bf16x8 __attribute__((ext_vector_type(8)));

__device__ __forceinline__ u16 f2bf(float f) {
  return __builtin_bit_cast(u16, (__bf16)f);
}
__device__ __forceinline__ float fexp2(float x) {
#if __has_builtin(__builtin_amdgcn_exp2f)
  return __builtin_amdgcn_exp2f(x);
#else
  return exp2f(x);
#endif
}
__device__ __forceinline__ f32x4 mfma16(u16x8 a, u16x8 b, f32x4 c) {
  return __builtin_amdgcn_mfma_f32_16x16x32_bf16(
      __builtin_bit_cast(bf16x8, a), __builtin_bit_cast(bf16x8, b), c, 0, 0, 0);
}
// async global->LDS, 16B/lane; LDS dest = wave-uniform base + lane*16 (implicit)
__device__ __forceinline__ void gload16(const void* g, void* l) {
  __builtin_amdgcn_global_load_lds(
      (const __attribute__((address_space(1))) void*)g,
      (__attribute__((address_space(3))) void*)l, 16, 0, 0);
}

// ---------------- cast pass: 4 W's fp32 -> bf16 (x casts fused into qkv) ----------------
__global__ void cast_w_k(
    const float* __restrict__ w0, const float* __restrict__ w1,
    const float* __restrict__ w2, const float* __restrict__ w3,
    u16* __restrict__ W0, u16* __restrict__ W1, u16* __restrict__ W2, u16* __restrict__ W3)
{
  const int NW = EMB*EMB/8;    // 73728
  int i = blockIdx.x*256 + threadIdx.x;
  if (i >= 4*NW) return;
  int which = i / NW, off = i - which*NW;
  const float* s = which==0 ? w0 : which==1 ? w1 : which==2 ? w2 : w3;
  u16* d        = which==0 ? W0 : which==1 ? W1 : which==2 ? W2 : W3;
  float4 a = reinterpret_cast<const float4*>(s)[off*2];
  float4 b = reinterpret_cast<const float4*>(s)[off*2+1];
  u16x8 o;
  o[0]=f2bf(a.x); o[1]=f2bf(a.y); o[2]=f2bf(a.z); o[3]=f2bf(a.w);
  o[4]=f2bf(b.x); o[5]=f2bf(b.y); o[6]=f2bf(b.z); o[7]=f2bf(b.w);
  reinterpret_cast<u16x8*>(d)[off] = o;
}

// ---------------- GEMM core: 64x128 tile, double-buffered, 1 barrier/step (r15) ----------------
template<int MODE, bool AF32>
__device__ __forceinline__ void gemm_core(
    const void* __restrict__ Ap, const u16* __restrict__ Bm,
    const float* __restrict__ bias, float ascale, float bscale,
    void* __restrict__ outp, u16* __restrict__ At, u16* __restrict__ Bt,
    int m0, int n0)
{
  const int t = threadIdx.x;
  const int w = t >> 6, lane = t & 63, lg = lane >> 4, lr = lane & 15;
  const int wr = w >> 1, wc = w & 1;
  const int lrow = lane >> 3, csl = lane & 7;

  f32x4 acc[2][4] = {};
  f32x4 raf[2][2];

  auto A_LOAD = [&](int kb) {
    #pragma unroll
    for (int q2 = 0; q2 < 2; ++q2) {
      int c = q2*256 + t, row = c >> 3, sl = c & 7;
      const float* p = (const float*)Ap + (size_t)(m0+row)*EMB + kb + sl*8;
      raf[q2][0] = *reinterpret_cast<const f32x4*>(p);
      raf[q2][1] = *reinterpret_cast<const f32x4*>(p + 4);
    }
  };
  auto A_WRITE = [&](int bi) {
    #pragma unroll
    for (int q2 = 0; q2 < 2; ++q2) {
      int c = q2*256 + t, row = c >> 3, sl = c & 7;
      u16x8 v;
      #pragma unroll
      for (int j = 0; j < 4; ++j) {
        v[j]   = f2bf(raf[q2][0][j] * ascale);
        v[4+j] = f2bf(raf[q2][1][j] * ascale);
      }
      *reinterpret_cast<u16x8*>(&At[bi*4096 + row*64 + ((sl ^ (row & 7))*8)]) = v;
    }
  };
  auto A_GLOAD = [&](int kb, int bi) {
    #pragma unroll
    for (int i = 0; i < 2; ++i) {
      int ci = w*2 + i;
      int row = ci*8 + lrow;
      int sg = csl ^ (row & 7);
      gload16((const u16*)Ap + (size_t)(m0+row)*EMB + kb + sg*8,
              &At[bi*4096 + ci*512]);
    }
  };
  auto B_GLOAD = [&](int kb, int bi) {
    #pragma unroll
    for (int i = 0; i < 4; ++i) {
      int ci = w*4 + i;
      int row = ci*8 + lrow;
      int sg = csl ^ (row & 7);
      gload16(Bm + (size_t)(n0+row)*EMB + kb + sg*8, &Bt[bi*8192 + ci*512]);
    }
  };

  auto COMPUTE = [&](int bi) {
    u16x8 af[2][2], bf[4][2];
    #pragma unroll
    for (int fm = 0; fm < 2; ++fm)
      #pragma unroll
      for (int kk = 0; kk < 2; ++kk) {
        int r = wr*32 + fm*16 + lr;
        int p = (lg + 4*kk) ^ (r & 7);
        af[fm][kk] = *reinterpret_cast<const u16x8*>(&At[bi*4096 + r*64 + p*8]);
      }
    #pragma unroll
    for (int fn = 0; fn < 4; ++fn)
      #pragma unroll
      for (int kk = 0; kk < 2; ++kk) {
        int r = wc*64 + fn*16 + lr;
        int p = (lg + 4*kk) ^ (r & 7);
        bf[fn][kk] = *reinterpret_cast<const u16x8*>(&Bt[bi*8192 + r*64 + p*8]);
      }
    __builtin_amdgcn_s_setprio(1);
    #pragma unroll
    for (int fm = 0; fm < 2; ++fm)
      #pragma unroll
      for (int fn = 0; fn < 4; ++fn)
        #pragma unroll
        for (int kk = 0; kk < 2; ++kk)
          acc[fm][fn] = mfma16(af[fm][kk], bf[fn][kk], acc[fm][fn]);
    __builtin_amdgcn_s_setprio(0);
  };

  const int NSTEP = EMB/64;   // 12
  if constexpr (AF32) {
    A_LOAD(0);
    B_GLOAD(0, 0);
    A_WRITE(0);
    __syncthreads();
    #pragma unroll
    for (int ts = 0; ts < NSTEP; ++ts) {
      if (ts+1 < NSTEP) {
        A_LOAD((ts+1)*64);
        B_GLOAD((ts+1)*64, (ts & 1) ^ 1);
      }
      COMPUTE(ts & 1);
      if (ts+1 < NSTEP) {
        A_WRITE((ts & 1) ^ 1);
        __syncthreads();
      }
    }
  } else {
    A_GLOAD(0, 0);
    B_GLOAD(0, 0);
    __syncthreads();
    #pragma unroll
    for (int ts = 0; ts < NSTEP; ++ts) {
      if (ts+1 < NSTEP) {
        A_GLOAD((ts+1)*64, (ts & 1) ^ 1);
        B_GLOAD((ts+1)*64, (ts & 1) ^ 1);
      }
      COMPUTE(ts & 1);
      if (ts+1 < NSTEP) __syncthreads();
    }
  }

  #pragma unroll
  for (int fm = 0; fm < 2; ++fm)
    #pragma unroll
    for (int fn = 0; fn < 4; ++fn) {
      const int mb = m0 + wr*32 + fm*16 + lg*4;
      const int e  = n0 + wc*64 + fn*16 + lr;
      if constexpr (MODE == 2) {
        int bb = mb >> 11, sb = mb & 2047, h = e >> 6, d = e & 63;
        u16x4 o4;
        #pragma unroll
        for (int j = 0; j < 4; ++j) o4[j] = f2bf(acc[fm][fn][j] + bias[e]*bscale);
        *reinterpret_cast<u16x4*>(
            reinterpret_cast<u16*>(outp) + (((size_t)(bb*HEADS+h))*DKV + d)*SEQ + sb) = o4;
      } else {
        #pragma unroll
        for (int j = 0; j < 4; ++j) {
          int m = mb + j;
          float val = acc[fm][fn][j] + bias[e]*bscale;
          if constexpr (MODE == 0) {
            int bb = m >> 11, s = m & 2047, h = e >> 6, d = e & 63;
            reinterpret_cast<u16*>(outp)[(((size_t)(bb*HEADS+h))*SEQ + s)*DKV + d] = f2bf(val);
          } else {
            reinterpret_cast<float*>(outp)[(size_t)m*EMB + e] = val;
          }
        }
      }
    }
}

__global__ __launch_bounds__(256) void qkv_k(
    const float* __restrict__ Xq, const float* __restrict__ Xk, const float* __restrict__ Xv,
    const u16* __restrict__ Wq, const u16* __restrict__ Wk, const u16* __restrict__ Wv,
    const float* __restrict__ bq, const float* __restrict__ bk, const float* __restrict__ bv,
    u16* __restrict__ Qh, u16* __restrict__ Kh, u16* __restrict__ Vh, float csc)
{
  __shared__ __align__(16) u16 At[2*64*64];
  __shared__ __align__(16) u16 Bt[2*128*64];
  const int m0 = blockIdx.x*64, n0 = blockIdx.y*128;
  const int z = blockIdx.z;
  if (z == 0)
    gemm_core<0,true>(Xq, Wq, bq, csc, csc, Qh, At, Bt, m0, n0);
  else if (z == 1)
    gemm_core<0,true>(Xk, Wk, bk, 1.f, 1.f, Kh, At, Bt, m0, n0);
  else
    gemm_core<2,true>(Xv, Wv, bv, 1.f, 1.f, Vh, At, Bt, m0, n0);
}

__global__ __launch_bounds__(256) void gemm_out_k(
    const u16* __restrict__ A, const u16* __restrict__ Bm,
    const float* __restrict__ bias, float* __restrict__ outp)
{
  __shared__ __align__(16) u16 At[2*64*64];
  __shared__ __align__(16) u16 Bt[2*128*64];
  gemm_core<1,false>(A, Bm, bias, 1.f, 1.f, outp, At, Bt, blockIdx.x*64, blockIdx.y*128);
}

// ---------------- flash attention: r15 structure + XCD-aware block decode (T1) ----------------
// 4 waves x 16 q-rows, swapped QK^T, per-lane base-2 softmax, partial-lrun,
// defer-max THR=8, K/V double-buffered via global_load_lds, ONE barrier/tile.
// NEW: 1D grid, decode id -> (bh, qb) so each XCD owns 3 contiguous bh
// (1.5 MB K/V per XCD L2 instead of all-bh everywhere): round-robin dispatch
// puts id%8 on XCD id%8; bh = (id&7)*3 + (id>>3)/32 is XCD-contiguous.
__global__ __launch_bounds__(256) void flash_attn_k(
    const u16* __restrict__ Q, const u16* __restrict__ K, const u16* __restrict__ VT,
    u16* __restrict__ av)
{
  __shared__ __align__(16) u16 Kt[2][64*64];     // [key][d]: phys p of row r = logical p^(r&7)
  __shared__ __align__(16) u16 Vt[2][64*64];     // [d][key]: same relation
  __shared__ __align__(16) u16 Pt[4][16*64];     // per-wave [q][k] swizzled

  const int t = threadIdx.x;
  const int w = t >> 6, lane = t & 63, lg = lane >> 4, lr = lane & 15;
  // XCD-aware decode (bijective over 768): xcd = id&7 owns bh 3*xcd..3*xcd+2
  const int id = blockIdx.x;
  const int j  = id >> 3;                  // 0..95
  const int bh = (id & 7)*3 + (j >> 5);    // 0..23
  const int qb = j & 31;                   // 0..31
  const u16* Qb = Q  + (size_t)bh*SEQ*DKV;
  const u16* Kb = K  + (size_t)bh*SEQ*DKV;
  const u16* Vb = VT + (size_t)bh*DKV*SEQ;

  const int qrow = qb*64 + w*16 + lr;
  u16x8 qf[2];
  qf[0] = *reinterpret_cast<const u16x8*>(Qb + (size_t)qrow*DKV + lg*8);
  qf[1] = *reinterpret_cast<const u16x8*>(Qb + (size_t)qrow*DKV + 32 + lg*8);

  f32x4 acc[4] = {};   // O^T: acc[fc][j] -> d = fc*16+lg*4+j, q = lr
  float mrun = -1e30f, lrun = 0.f;   // lrun = per-lane PARTIAL (16 keys/tile)

  auto STAGE = [&](int kt0, int bi) {
    #pragma unroll
    for (int c2 = 0; c2 < 2; ++c2) {
      int c = c2*256 + t;                 // 16B chunk 0..511
      int row = c >> 3, sl = c & 7;
      int sg = sl ^ (row & 7);            // pre-swizzled source slot
      gload16(Kb + (size_t)(kt0+row)*DKV + sg*8, &Kt[bi][c*8]);
    }
    #pragma unroll
    for (int c2 = 0; c2 < 2; ++c2) {
      int c = c2*256 + t;
      int row = c >> 3, sl = c & 7;       // row = d
      int sg = sl ^ (row & 7);
      gload16(Vb + (size_t)row*SEQ + kt0 + sg*8, &Vt[bi][c*8]);
    }
  };

  const int NT = SEQ/64;   // 32
  char* Pw = reinterpret_cast<char*>(&Pt[w][0]);

#define TILE(bi, kt)                                                          \
  do {                                                                        \
    if ((kt)+1 < NT) STAGE(((kt)+1)*64, (bi)^1);  /* async into other buf */  \
    f32x4 s[4];                                                               \
    __builtin_amdgcn_s_setprio(1);                                            \
    _Pragma("unroll")                                                         \
    for (int fc = 0; fc < 4; ++fc) {                                          \
      f32x4 z = {};                                                           \
      _Pragma("unroll")                                                       \
      for (int kk = 0; kk < 2; ++kk) {                                        \
        int r = fc*16 + lr;                                                   \
        int slot = (lg + 4*kk) ^ (r & 7);                                     \
        u16x8 kf = *reinterpret_cast<const u16x8*>(&Kt[bi][r*64 + slot*8]);   \
        z = mfma16(kf, qf[kk], z);                                            \
      }                                                                       \
      s[fc] = z;                                                              \
    }                                                                         \
    __builtin_amdgcn_s_setprio(0);                                            \
    float a0 = fmaxf(fmaxf(s[0][0], s[0][1]), s[0][2]);                       \
    float a1 = fmaxf(fmaxf(s[0][3], s[1][0]), s[1][1]);                       \
    float a2 = fmaxf(fmaxf(s[1][2], s[1][3]), s[2][0]);                       \
    float a3 = fmaxf(fmaxf(s[2][1], s[2][2]), s[2][3]);                       \
    float a4 = fmaxf(fmaxf(s[3][0], s[3][1]), s[3][2]);                       \
    float pmax = fmaxf(fmaxf(fmaxf(a0, a1), a2),                              \
                       fmaxf(fmaxf(a3, a4), s[3][3]));                        \
    if (__any(pmax > mrun + 8.f)) {   /* rare: full reduce + rescale */       \
      float pm = fmaxf(pmax, __shfl_xor(pmax, 16));                           \
      pm = fmaxf(pm, __shfl_xor(pm, 32));                                     \
      float mnew = fmaxf(mrun, pm);                                           \
      float corr = fexp2(mrun - mnew);                                        \
      mrun = mnew; lrun *= corr;                                              \
      _Pragma("unroll")                                                       \
      for (int fc = 0; fc < 4; ++fc)                                          \
        _Pragma("unroll")                                                     \
        for (int j2 = 0; j2 < 4; ++j2)                                        \
          acc[fc][j2] *= corr;                                                \
    }                                                                         \
    float p[4][4], rs[4];                                                     \
    _Pragma("unroll")                                                         \
    for (int fc = 0; fc < 4; ++fc) {                                          \
      _Pragma("unroll")                                                       \
      for (int j2 = 0; j2 < 4; ++j2) p[fc][j2] = fexp2(s[fc][j2] - mrun);     \
      rs[fc] = (p[fc][0] + p[fc][1]) + (p[fc][2] + p[fc][3]);                 \
    }                                                                         \
    lrun += (rs[0] + rs[1]) + (rs[2] + rs[3]);   /* partial: no shuffles */   \
    _Pragma("unroll")                                                         \
    for (int fc = 0; fc < 4; ++fc) {                                          \
      u16x4 q4;                                                               \
      _Pragma("unroll")                                                       \
      for (int j2 = 0; j2 < 4; ++j2) q4[j2] = f2bf(p[fc][j2]);                \
      *reinterpret_cast<u16x4*>(                                              \
          Pw + lr*128 + (((fc*4 + lg) ^ ((lr & 7) << 1))*8)) = q4;            \
    }                                                                         \
    asm volatile("s_waitcnt lgkmcnt(0)" ::: "memory");                        \
    __builtin_amdgcn_sched_barrier(0);                                        \
    __builtin_amdgcn_s_setprio(1);                                            \
    _Pragma("unroll")                                                         \
    for (int kk = 0; kk < 2; ++kk) {                                          \
      u16x8 pf = *reinterpret_cast<const u16x8*>(                             \
          Pw + lr*128 + (((kk*8 + lg*2) ^ ((lr & 7) << 1))*8));               \
      _Pragma("unroll")                                                       \
      for (int fc = 0; fc < 4; ++fc) {                                        \
        int rv = fc*16 + lr;                                                  \
        int slotv = (lg + 4*kk) ^ (rv & 7);                                   \
        u16x8 vf = *reinterpret_cast<const u16x8*>(&Vt[bi][rv*64 + slotv*8]); \
        acc[fc] = mfma16(vf, pf, acc[fc]);                                    \
      }                                                                       \
    }                                                                         \
    __builtin_amdgcn_s_setprio(0);                                            \
    __syncthreads();   /* drains gloads into buf^1 + all waves done with buf */\
  } while (0)

  STAGE(0, 0);
  __syncthreads();
  for (int kt = 0; kt < NT; kt += 2) {
    TILE(0, kt);
    TILE(1, kt+1);
  }
#undef TILE

  // epilogue: combine partial l across the 4 lg-lanes of each q-row, normalize
  float lt = lrun;
  lt += __shfl_xor(lt, 16);
  lt += __shfl_xor(lt, 32);
  const float inv = 1.0f / lt;

  const int b = bh / HEADS, h = bh % HEADS;
  #pragma unroll
  for (int fc = 0; fc < 4; ++fc) {
    u16x4 o4;
    #pragma unroll
    for (int j = 0; j < 4; ++j) o4[j] = f2bf(acc[fc][j] * inv);
    *reinterpret_cast<u16x4*>(
        av + ((size_t)(b*SEQ + qrow))*EMB + h*64 + fc*16 + lg*4) = o4;
  }
}

// ---------------- launcher: 4 kernels ----------------
extern "C" void kernel_launch(void* const* d_in, const int* in_sizes, int n_in,
                              void* d_out, int out_size, void* d_ws, size_t ws_size,
                              hipStream_t stream) {
  const float* xq_f = (const float*)d_in[0];
  const float* xk_f = (const float*)d_in[1];
  const float* xv_f = (const float*)d_in[2];
  const float* Wq = (const float*)d_in[3];
  const float* bq = (const float*)d_in[4];
  const float* Wk = (const float*)d_in[5];
  const float* bk = (const float*)d_in[6];
  const float* Wv = (const float*)d_in[7];
  const float* bv = (const float*)d_in[8];
  const float* Wo = (const float*)d_in[9];
  const float* bo = (const float*)d_in[10];

  const size_t NX = (size_t)NTOK*EMB;
  const size_t NW = (size_t)EMB*EMB;
  u16* Wc0 = (u16*)d_ws;
  u16* Wc1 = Wc0 + NW;
  u16* Wc2 = Wc1 + NW;
  u16* Wc3 = Wc2 + NW;
  u16* Qh  = Wc3 + NW;
  u16* Kh  = Qh + NX;
  u16* Vh  = Kh + NX;        // [B][H][DKV][SEQ] (V^T)
  u16* Xb  = Vh + NX;        // attn output bf16

  const float csc = 0.125f * 1.4426950408889634f;  // folded into Q A-tile + bq

  cast_w_k<<<dim3(4*EMB*EMB/8/256), dim3(256), 0, stream>>>(
      Wq, Wk, Wv, Wo, Wc0, Wc1, Wc2, Wc3);

  qkv_k<<<dim3(NTOK/64, EMB/128, 3), dim3(256), 0, stream>>>(
      xq_f, xk_f, xv_f, Wc0, Wc1, Wc2, bq, bk, bv, Qh, Kh, Vh, csc);

  flash_attn_k<<<dim3(SEQ/64 * BATCH*HEADS), dim3(256), 0, stream>>>(Qh, Kh, Vh, Xb);

  gemm_out_k<<<dim3(NTOK/64, EMB/128), dim3(256), 0, stream>>>(Xb, Wc3, bo, (float*)d_out);
}

// Round 18
// 94.873 us; speedup vs baseline: 1.1170x; 1.0023x over previous
//
#include <hip/hip_runtime.h>
#include <hip/hip_bf16.h>

#define EMB 768
#define HEADS 12
#define DKV 64
#define BATCH 2
#define SEQ 2048
#define NTOK (BATCH*SEQ)   // 4096

typedef float f32x4 __attribute__((ext_vector_type(4)));
typedef unsigned short u16;
typedef u16 u16x8 __attribute__((ext_vector_type(8)));
typedef u16 u16x4 __attribute__((ext_vector_type(4)));
typedef __bf16 bf16x8 __attribute__((ext_vector_type(8)));

__device__ __forceinline__ u16 f2bf(float f) {
  return __builtin_bit_cast(u16, (__bf16)f);
}
__device__ __forceinline__ float fexp2(float x) {
#if __has_builtin(__builtin_amdgcn_exp2f)
  return __builtin_amdgcn_exp2f(x);
#else
  return exp2f(x);
#endif
}
__device__ __forceinline__ f32x4 mfma16(u16x8 a, u16x8 b, f32x4 c) {
  return __builtin_amdgcn_mfma_f32_16x16x32_bf16(
      __builtin_bit_cast(bf16x8, a), __builtin_bit_cast(bf16x8, b), c, 0, 0, 0);
}
// async global->LDS, 16B/lane; LDS dest = wave-uniform base + lane*16 (implicit)
__device__ __forceinline__ void gload16(const void* g, void* l) {
  __builtin_amdgcn_global_load_lds(
      (const __attribute__((address_space(1))) void*)g,
      (__attribute__((address_space(3))) void*)l, 16, 0, 0);
}

// ---------------- cast pass: 4 W's fp32 -> bf16 (x casts fused into qkv) ----------------
__global__ void cast_w_k(
    const float* __restrict__ w0, const float* __restrict__ w1,
    const float* __restrict__ w2, const float* __restrict__ w3,
    u16* __restrict__ W0, u16* __restrict__ W1, u16* __restrict__ W2, u16* __restrict__ W3)
{
  const int NW = EMB*EMB/8;    // 73728
  int i = blockIdx.x*256 + threadIdx.x;
  if (i >= 4*NW) return;
  int which = i / NW, off = i - which*NW;
  const float* s = which==0 ? w0 : which==1 ? w1 : which==2 ? w2 : w3;
  u16* d        = which==0 ? W0 : which==1 ? W1 : which==2 ? W2 : W3;
  float4 a = reinterpret_cast<const float4*>(s)[off*2];
  float4 b = reinterpret_cast<const float4*>(s)[off*2+1];
  u16x8 o;
  o[0]=f2bf(a.x); o[1]=f2bf(a.y); o[2]=f2bf(a.z); o[3]=f2bf(a.w);
  o[4]=f2bf(b.x); o[5]=f2bf(b.y); o[6]=f2bf(b.z); o[7]=f2bf(b.w);
  reinterpret_cast<u16x8*>(d)[off] = o;
}

// ---------------- GEMM core: 64x128 tile, double-buffered, 1 barrier/step (r15) ----------------
template<int MODE, bool AF32>
__device__ __forceinline__ void gemm_core(
    const void* __restrict__ Ap, const u16* __restrict__ Bm,
    const float* __restrict__ bias, float ascale, float bscale,
    void* __restrict__ outp, u16* __restrict__ At, u16* __restrict__ Bt,
    int m0, int n0)
{
  const int t = threadIdx.x;
  const int w = t >> 6, lane = t & 63, lg = lane >> 4, lr = lane & 15;
  const int wr = w >> 1, wc = w & 1;
  const int lrow = lane >> 3, csl = lane & 7;

  f32x4 acc[2][4] = {};
  f32x4 raf[2][2];

  auto A_LOAD = [&](int kb) {
    #pragma unroll
    for (int q2 = 0; q2 < 2; ++q2) {
      int c = q2*256 + t, row = c >> 3, sl = c & 7;
      const float* p = (const float*)Ap + (size_t)(m0+row)*EMB + kb + sl*8;
      raf[q2][0] = *reinterpret_cast<const f32x4*>(p);
      raf[q2][1] = *reinterpret_cast<const f32x4*>(p + 4);
    }
  };
  auto A_WRITE = [&](int bi) {
    #pragma unroll
    for (int q2 = 0; q2 < 2; ++q2) {
      int c = q2*256 + t, row = c >> 3, sl = c & 7;
      u16x8 v;
      #pragma unroll
      for (int j = 0; j < 4; ++j) {
        v[j]   = f2bf(raf[q2][0][j] * ascale);
        v[4+j] = f2bf(raf[q2][1][j] * ascale);
      }
      *reinterpret_cast<u16x8*>(&At[bi*4096 + row*64 + ((sl ^ (row & 7))*8)]) = v;
    }
  };
  auto A_GLOAD = [&](int kb, int bi) {
    #pragma unroll
    for (int i = 0; i < 2; ++i) {
      int ci = w*2 + i;
      int row = ci*8 + lrow;
      int sg = csl ^ (row & 7);
      gload16((const u16*)Ap + (size_t)(m0+row)*EMB + kb + sg*8,
              &At[bi*4096 + ci*512]);
    }
  };
  auto B_GLOAD = [&](int kb, int bi) {
    #pragma unroll
    for (int i = 0; i < 4; ++i) {
      int ci = w*4 + i;
      int row = ci*8 + lrow;
      int sg = csl ^ (row & 7);
      gload16(Bm + (size_t)(n0+row)*EMB + kb + sg*8, &Bt[bi*8192 + ci*512]);
    }
  };

  auto COMPUTE = [&](int bi) {
    u16x8 af[2][2], bf[4][2];
    #pragma unroll
    for (int fm = 0; fm < 2; ++fm)
      #pragma unroll
      for (int kk = 0; kk < 2; ++kk) {
        int r = wr*32 + fm*16 + lr;
        int p = (lg + 4*kk) ^ (r & 7);
        af[fm][kk] = *reinterpret_cast<const u16x8*>(&At[bi*4096 + r*64 + p*8]);
      }
    #pragma unroll
    for (int fn = 0; fn < 4; ++fn)
      #pragma unroll
      for (int kk = 0; kk < 2; ++kk) {
        int r = wc*64 + fn*16 + lr;
        int p = (lg + 4*kk) ^ (r & 7);
        bf[fn][kk] = *reinterpret_cast<const u16x8*>(&Bt[bi*8192 + r*64 + p*8]);
      }
    __builtin_amdgcn_s_setprio(1);
    #pragma unroll
    for (int fm = 0; fm < 2; ++fm)
      #pragma unroll
      for (int fn = 0; fn < 4; ++fn)
        #pragma unroll
        for (int kk = 0; kk < 2; ++kk)
          acc[fm][fn] = mfma16(af[fm][kk], bf[fn][kk], acc[fm][fn]);
    __builtin_amdgcn_s_setprio(0);
  };

  const int NSTEP = EMB/64;   // 12
  if constexpr (AF32) {
    A_LOAD(0);
    B_GLOAD(0, 0);
    A_WRITE(0);
    __syncthreads();
    #pragma unroll
    for (int ts = 0; ts < NSTEP; ++ts) {
      if (ts+1 < NSTEP) {
        A_LOAD((ts+1)*64);
        B_GLOAD((ts+1)*64, (ts & 1) ^ 1);
      }
      COMPUTE(ts & 1);
      if (ts+1 < NSTEP) {
        A_WRITE((ts & 1) ^ 1);
        __syncthreads();
      }
    }
  } else {
    A_GLOAD(0, 0);
    B_GLOAD(0, 0);
    __syncthreads();
    #pragma unroll
    for (int ts = 0; ts < NSTEP; ++ts) {
      if (ts+1 < NSTEP) {
        A_GLOAD((ts+1)*64, (ts & 1) ^ 1);
        B_GLOAD((ts+1)*64, (ts & 1) ^ 1);
      }
      COMPUTE(ts & 1);
      if (ts+1 < NSTEP) __syncthreads();
    }
  }

  #pragma unroll
  for (int fm = 0; fm < 2; ++fm)
    #pragma unroll
    for (int fn = 0; fn < 4; ++fn) {
      const int mb = m0 + wr*32 + fm*16 + lg*4;
      const int e  = n0 + wc*64 + fn*16 + lr;
      if constexpr (MODE == 2) {
        int bb = mb >> 11, sb = mb & 2047, h = e >> 6, d = e & 63;
        u16x4 o4;
        #pragma unroll
        for (int j = 0; j < 4; ++j) o4[j] = f2bf(acc[fm][fn][j] + bias[e]*bscale);
        *reinterpret_cast<u16x4*>(
            reinterpret_cast<u16*>(outp) + (((size_t)(bb*HEADS+h))*DKV + d)*SEQ + sb) = o4;
      } else {
        #pragma unroll
        for (int j = 0; j < 4; ++j) {
          int m = mb + j;
          float val = acc[fm][fn][j] + bias[e]*bscale;
          if constexpr (MODE == 0) {
            int bb = m >> 11, s = m & 2047, h = e >> 6, d = e & 63;
            reinterpret_cast<u16*>(outp)[(((size_t)(bb*HEADS+h))*SEQ + s)*DKV + d] = f2bf(val);
          } else {
            reinterpret_cast<float*>(outp)[(size_t)m*EMB + e] = val;
          }
        }
      }
    }
}

__global__ __launch_bounds__(256) void qkv_k(
    const float* __restrict__ Xq, const float* __restrict__ Xk, const float* __restrict__ Xv,
    const u16* __restrict__ Wq, const u16* __restrict__ Wk, const u16* __restrict__ Wv,
    const float* __restrict__ bq, const float* __restrict__ bk, const float* __restrict__ bv,
    u16* __restrict__ Qh, u16* __restrict__ Kh, u16* __restrict__ Vh, float csc)
{
  __shared__ __align__(16) u16 At[2*64*64];
  __shared__ __align__(16) u16 Bt[2*128*64];
  const int m0 = blockIdx.x*64, n0 = blockIdx.y*128;
  const int z = blockIdx.z;
  if (z == 0)
    gemm_core<0,true>(Xq, Wq, bq, csc, csc, Qh, At, Bt, m0, n0);
  else if (z == 1)
    gemm_core<0,true>(Xk, Wk, bk, 1.f, 1.f, Kh, At, Bt, m0, n0);
  else
    gemm_core<2,true>(Xv, Wv, bv, 1.f, 1.f, Vh, At, Bt, m0, n0);
}

__global__ __launch_bounds__(256) void gemm_out_k(
    const u16* __restrict__ A, const u16* __restrict__ Bm,
    const float* __restrict__ bias, float* __restrict__ outp)
{
  __shared__ __align__(16) u16 At[2*64*64];
  __shared__ __align__(16) u16 Bt[2*128*64];
  gemm_core<1,false>(A, Bm, bias, 1.f, 1.f, outp, At, Bt, blockIdx.x*64, blockIdx.y*128);
}

// ---------------- flash attention: 8 waves x 16 q-rows (128 q/block) + XCD decode ----------------
// Per-wave code IDENTICAL to r17 (proven). 8 waves share each K/V tile (staging
// amortized 2x) and the grid drops to 384 blocks — ALL co-resident (LDS 48 KB ->
// 3 blocks/CU cap), busiest CUs get 16 waves (4/SIMD, up from 3) of independent
// chains. VGPR ~60 unchanged. XCD decode: xcd=id&7 owns bh 3*xcd..3*xcd+2.
__global__ __launch_bounds__(512) void flash_attn_k(
    const u16* __restrict__ Q, const u16* __restrict__ K, const u16* __restrict__ VT,
    u16* __restrict__ av)
{
  __shared__ __align__(16) u16 Kt[2][64*64];     // [key][d]: phys p of row r = logical p^(r&7)
  __shared__ __align__(16) u16 Vt[2][64*64];     // [d][key]: same relation
  __shared__ __align__(16) u16 Pt[8][16*64];     // per-wave [q][k] swizzled

  const int t = threadIdx.x;                     // 0..511
  const int w = t >> 6, lane = t & 63, lg = lane >> 4, lr = lane & 15;
  // XCD-aware decode (bijective over 384): xcd = id&7; j = id>>3 in 0..47
  const int id = blockIdx.x;
  const int j  = id >> 3;                  // 0..47
  const int bh = (id & 7)*3 + (j >> 4);    // 0..23
  const int qb = j & 15;                   // 0..15 (128-row q blocks)
  const u16* Qb = Q  + (size_t)bh*SEQ*DKV;
  const u16* Kb = K  + (size_t)bh*SEQ*DKV;
  const u16* Vb = VT + (size_t)bh*DKV*SEQ;

  const int qrow = qb*128 + w*16 + lr;
  u16x8 qf[2];
  qf[0] = *reinterpret_cast<const u16x8*>(Qb + (size_t)qrow*DKV + lg*8);
  qf[1] = *reinterpret_cast<const u16x8*>(Qb + (size_t)qrow*DKV + 32 + lg*8);

  f32x4 acc[4] = {};   // O^T: acc[fc][j] -> d = fc*16+lg*4+j, q = lr
  float mrun = -1e30f, lrun = 0.f;   // lrun = per-lane PARTIAL (16 keys/tile)

  auto STAGE = [&](int kt0, int bi) {
    // 512 threads: one 16B K-chunk + one 16B V-chunk per thread
    int c = t;                            // 16B chunk 0..511
    int row = c >> 3, sl = c & 7;
    int sg = sl ^ (row & 7);              // pre-swizzled source slot
    gload16(Kb + (size_t)(kt0+row)*DKV + sg*8, &Kt[bi][c*8]);
    gload16(Vb + (size_t)row*SEQ + kt0 + sg*8, &Vt[bi][c*8]);
  };

  const int NT = SEQ/64;   // 32
  char* Pw = reinterpret_cast<char*>(&Pt[w][0]);

#define TILE(bi, kt)                                                          \
  do {                                                                        \
    if ((kt)+1 < NT) STAGE(((kt)+1)*64, (bi)^1);  /* async into other buf */  \
    f32x4 s[4];                                                               \
    __builtin_amdgcn_s_setprio(1);                                            \
    _Pragma("unroll")                                                         \
    for (int fc = 0; fc < 4; ++fc) {                                          \
      f32x4 z = {};                                                           \
      _Pragma("unroll")                                                       \
      for (int kk = 0; kk < 2; ++kk) {                                        \
        int r = fc*16 + lr;                                                   \
        int slot = (lg + 4*kk) ^ (r & 7);                                     \
        u16x8 kf = *reinterpret_cast<const u16x8*>(&Kt[bi][r*64 + slot*8]);   \
        z = mfma16(kf, qf[kk], z);                                            \
      }                                                                       \
      s[fc] = z;                                                              \
    }                                                                         \
    __builtin_amdgcn_s_setprio(0);                                            \
    float a0 = fmaxf(fmaxf(s[0][0], s[0][1]), s[0][2]);                       \
    float a1 = fmaxf(fmaxf(s[0][3], s[1][0]), s[1][1]);                       \
    float a2 = fmaxf(fmaxf(s[1][2], s[1][3]), s[2][0]);                       \
    float a3 = fmaxf(fmaxf(s[2][1], s[2][2]), s[2][3]);                       \
    float a4 = fmaxf(fmaxf(s[3][0], s[3][1]), s[3][2]);                       \
    float pmax = fmaxf(fmaxf(fmaxf(a0, a1), a2),                              \
                       fmaxf(fmaxf(a3, a4), s[3][3]));                        \
    if (__any(pmax > mrun + 8.f)) {   /* rare: full reduce + rescale */       \
      float pm = fmaxf(pmax, __shfl_xor(pmax, 16));                           \
      pm = fmaxf(pm, __shfl_xor(pm, 32));                                     \
      float mnew = fmaxf(mrun, pm);                                           \
      float corr = fexp2(mrun - mnew);                                        \
      mrun = mnew; lrun *= corr;                                              \
      _Pragma("unroll")                                                       \
      for (int fc = 0; fc < 4; ++fc)                                          \
        _Pragma("unroll")                                                     \
        for (int j2 = 0; j2 < 4; ++j2)                                        \
          acc[fc][j2] *= corr;                                                \
    }                                                                         \
    float p[4][4], rs[4];                                                     \
    _Pragma("unroll")                                                         \
    for (int fc = 0; fc < 4; ++fc) {                                          \
      _Pragma("unroll")                                                       \
      for (int j2 = 0; j2 < 4; ++j2) p[fc][j2] = fexp2(s[fc][j2] - mrun);     \
      rs[fc] = (p[fc][0] + p[fc][1]) + (p[fc][2] + p[fc][3]);                 \
    }                                                                         \
    lrun += (rs[0] + rs[1]) + (rs[2] + rs[3]);   /* partial: no shuffles */   \
    _Pragma("unroll")                                                         \
    for (int fc = 0; fc < 4; ++fc) {                                          \
      u16x4 q4;                                                               \
      _Pragma("unroll")                                                       \
      for (int j2 = 0; j2 < 4; ++j2) q4[j2] = f2bf(p[fc][j2]);                \
      *reinterpret_cast<u16x4*>(                                              \
          Pw + lr*128 + (((fc*4 + lg) ^ ((lr & 7) << 1))*8)) = q4;            \
    }                                                                         \
    asm volatile("s_waitcnt lgkmcnt(0)" ::: "memory");                        \
    __builtin_amdgcn_sched_barrier(0);                                        \
    __builtin_amdgcn_s_setprio(1);                                            \
    _Pragma("unroll")                                                         \
    for (int kk = 0; kk < 2; ++kk) {                                          \
      u16x8 pf = *reinterpret_cast<const u16x8*>(                             \
          Pw + lr*128 + (((kk*8 + lg*2) ^ ((lr & 7) << 1))*8));               \
      _Pragma("unroll")                                                       \
      for (int fc = 0; fc < 4; ++fc) {                                        \
        int rv = fc*16 + lr;                                                  \
        int slotv = (lg + 4*kk) ^ (rv & 7);                                   \
        u16x8 vf = *reinterpret_cast<const u16x8*>(&Vt[bi][rv*64 + slotv*8]); \
        acc[fc] = mfma16(vf, pf, acc[fc]);                                    \
      }                                                                       \
    }                                                                         \
    __builtin_amdgcn_s_setprio(0);                                            \
    __syncthreads();   /* drains gloads into buf^1 + all waves done with buf */\
  } while (0)

  STAGE(0, 0);
  __syncthreads();
  for (int kt = 0; kt < NT; kt += 2) {
    TILE(0, kt);
    TILE(1, kt+1);
  }
#undef TILE

  // epilogue: combine partial l across the 4 lg-lanes of each q-row, normalize
  float lt = lrun;
  lt += __shfl_xor(lt, 16);
  lt += __shfl_xor(lt, 32);
  const float inv = 1.0f / lt;

  const int b = bh / HEADS, h = bh % HEADS;
  #pragma unroll
  for (int fc = 0; fc < 4; ++fc) {
    u16x4 o4;
    #pragma unroll
    for (int j2 = 0; j2 < 4; ++j2) o4[j2] = f2bf(acc[fc][j2] * inv);
    *reinterpret_cast<u16x4*>(
        av + ((size_t)(b*SEQ + qrow))*EMB + h*64 + fc*16 + lg*4) = o4;
  }
}

// ---------------- launcher: 4 kernels ----------------
extern "C" void kernel_launch(void* const* d_in, const int* in_sizes, int n_in,
                              void* d_out, int out_size, void* d_ws, size_t ws_size,
                              hipStream_t stream) {
  const float* xq_f = (const float*)d_in[0];
  const float* xk_f = (const float*)d_in[1];
  const float* xv_f = (const float*)d_in[2];
  const float* Wq = (const float*)d_in[3];
  const float* bq = (const float*)d_in[4];
  const float* Wk = (const float*)d_in[5];
  const float* bk = (const float*)d_in[6];
  const float* Wv = (const float*)d_in[7];
  const float* bv = (const float*)d_in[8];
  const float* Wo = (const float*)d_in[9];
  const float* bo = (const float*)d_in[10];

  const size_t NX = (size_t)NTOK*EMB;
  const size_t NW = (size_t)EMB*EMB;
  u16* Wc0 = (u16*)d_ws;
  u16* Wc1 = Wc0 + NW;
  u16* Wc2 = Wc1 + NW;
  u16* Wc3 = Wc2 + NW;
  u16* Qh  = Wc3 + NW;
  u16* Kh  = Qh + NX;
  u16* Vh  = Kh + NX;        // [B][H][DKV][SEQ] (V^T)
  u16* Xb  = Vh + NX;        // attn output bf16

  const float csc = 0.125f * 1.4426950408889634f;  // folded into Q A-tile + bq

  cast_w_k<<<dim3(4*EMB*EMB/8/256), dim3(256), 0, stream>>>(
      Wq, Wk, Wv, Wo, Wc0, Wc1, Wc2, Wc3);

  qkv_k<<<dim3(NTOK/64, EMB/128, 3), dim3(256), 0, stream>>>(
      xq_f, xk_f, xv_f, Wc0, Wc1, Wc2, bq, bk, bv, Qh, Kh, Vh, csc);

  flash_attn_k<<<dim3(SEQ/128 * BATCH*HEADS), dim3(512), 0, stream>>>(Qh, Kh, Vh, Xb);

  gemm_out_k<<<dim3(NTOK/64, EMB/128), dim3(256), 0, stream>>>(Xb, Wc3, bo, (float*)d_out);
}